// Round 2
// baseline (221.129 us; speedup 1.0000x reference)
//
#include <hip/hip_runtime.h>

#define GC 32768
#define GN (2*GC)
#define GE (3*GC-2)

// Folded constants: g_fold[0..15] = wmu[0:16] @ w3b, g_fold[16] = wmu[0:16] . b3b
__device__ float g_fold[17];

__global__ void fold_setup(const float* __restrict__ w3b, const float* __restrict__ b3b,
                           const float* __restrict__ wmu) {
    int h = threadIdx.x;
    if (h < 16) {
        float a = 0.f;
        for (int o = 0; o < 16; ++o) a = fmaf(wmu[o], w3b[o * 16 + h], a);
        g_fold[h] = a;
    } else if (h == 16) {
        float a = 0.f;
        for (int o = 0; o < 16; ++o) a = fmaf(wmu[o], b3b[o], a);
        g_fold[16] = a;
    }
}

// out[h] = sum_k f[k] * W[h][col0+k]
template<int F, int H, int IN>
__device__ __forceinline__ void projF(const float* f, const float* __restrict__ W,
                                      int col0, float* out) {
#pragma unroll
    for (int h = 0; h < H; ++h) {
        const float* w = W + h * IN + col0;
        float a = f[0] * w[0];
#pragma unroll
        for (int k = 1; k < F; ++k) a = fmaf(f[k], w[k], a);
        out[h] = a;
    }
}

// acc[h] += sum_k f[k] * W[h][col0+k]
template<int F, int H, int IN>
__device__ __forceinline__ void accF(const float* f, const float* __restrict__ W,
                                     int col0, float* acc) {
#pragma unroll
    for (int h = 0; h < H; ++h) {
        const float* w = W + h * IN + col0;
        float a = acc[h];
#pragma unroll
        for (int k = 0; k < F; ++k) a = fmaf(f[k], w[k], a);
        acc[h] = a;
    }
}

// out[h] = B[h] + sum_k e4[k] * W[h][IN-4+k]   (e-projection seeded with bias)
template<int H, int IN>
__device__ __forceinline__ void projE(const float* e4, const float* __restrict__ W,
                                      const float* __restrict__ B, float* out) {
#pragma unroll
    for (int h = 0; h < H; ++h) {
        const float* w = W + h * IN + (IN - 4);
        float a = B[h];
#pragma unroll
        for (int k = 0; k < 4; ++k) a = fmaf(e4[k], w[k], a);
        out[h] = a;
    }
}

// out[o] = B2[o] + sum_h relu(a[h]+b[h]) * W2[o][h]
template<int H, int O>
__device__ __forceinline__ void zgemm2(const float* a, const float* b,
                                       const float* __restrict__ W2,
                                       const float* __restrict__ B2, float* out) {
    float z[H];
#pragma unroll
    for (int h = 0; h < H; ++h) z[h] = fmaxf(a[h] + b[h], 0.f);
#pragma unroll
    for (int o = 0; o < O; ++o) {
        float acc = B2[o];
#pragma unroll
        for (int h = 0; h < H; ++h) acc = fmaf(z[h], W2[o * H + h], acc);
        out[o] = acc;
    }
}

// out[o] = B2[o] + sum_h relu(a[h]+b[h]+c[h]) * W2[o][h]
template<int H, int O>
__device__ __forceinline__ void zgemm3(const float* a, const float* b, const float* c,
                                       const float* __restrict__ W2,
                                       const float* __restrict__ B2, float* out) {
    float z[H];
#pragma unroll
    for (int h = 0; h < H; ++h) z[h] = fmaxf(a[h] + b[h] + c[h], 0.f);
#pragma unroll
    for (int o = 0; o < O; ++o) {
        float acc = B2[o];
#pragma unroll
        for (int h = 0; h < H; ++h) acc = fmaf(z[h], W2[o * H + h], acc);
        out[o] = acc;
    }
}

// One edge-conv layer with per-node projection sharing.
// f0/f1: this column's features (row0/row1). h0/h1o: outputs.
template<int F, int H, int IN, int O>
__device__ __forceinline__ void layer(const float* f0, const float* f1,
                                      const float* e1, const float* e2, const float* e3,
                                      const float* __restrict__ W1, const float* __restrict__ B1,
                                      const float* __restrict__ W2, const float* __restrict__ B2,
                                      bool jpos, float* h0, float* h1o) {
    float S0[H], S1[H];
    projF<F, H, IN>(f0, W1, F, S0);     // src-proj of row0 (used by vertical + next col's h1)
    projF<F, H, IN>(f1, W1, F, S1);     // src-proj of row1 (used by next col's h2)
    float S0p[H], S1p[H];
#pragma unroll
    for (int i = 0; i < H; ++i) { S0p[i] = __shfl_up(S0[i], 1); S1p[i] = __shfl_up(S1[i], 1); }

    float t[H];
    // row0 horizontal edge: z = (We@e1 + b1 + Wd@f0) + S0p
    projE<H, IN>(e1, W1, B1, t);
    accF<F, H, IN>(f0, W1, 0, t);
    float A[O];
    zgemm2<H, O>(t, S0p, W2, B2, A);

    float P1[H];
    projF<F, H, IN>(f1, W1, 0, P1);     // dst-proj of row1, shared by h2 + vertical

    // row1 horizontal edge
    projE<H, IN>(e2, W1, B1, t);
    float Bv[O];
    zgemm3<H, O>(t, P1, S1p, W2, B2, Bv);

    // vertical edge (dst=row1, src=row0)
    projE<H, IN>(e3, W1, B1, t);
    float V[O];
    zgemm3<H, O>(t, P1, S0, W2, B2, V);

#pragma unroll
    for (int o = 0; o < O; ++o) {
        h0[o]  = jpos ? A[o] : 0.f;
        h1o[o] = jpos ? fmaxf(V[o], Bv[o]) : V[o];
    }
}

__global__ __launch_bounds__(256) void gnn_fused(
    const float* __restrict__ x, const float* __restrict__ e,
    const float* __restrict__ w1a, const float* __restrict__ b1a,
    const float* __restrict__ w1b, const float* __restrict__ b1b,
    const float* __restrict__ w2a, const float* __restrict__ b2a,
    const float* __restrict__ w2b, const float* __restrict__ b2b,
    const float* __restrict__ w3a, const float* __restrict__ b3a,
    const float* __restrict__ w3b, const float* __restrict__ b3b,
    const float* __restrict__ wmu, const float* __restrict__ bmu,
    float* __restrict__ out)
{
    constexpr int COLS = 61;                     // valid columns per wave (3 halo lanes)
    constexpr int WPB = (GC + COLS - 1) / COLS;  // 538 waves per batch row
    const int gtid = blockIdx.x * blockDim.x + threadIdx.x;
    const int wave = gtid >> 6;
    const int lane = gtid & 63;
    const int b    = wave / WPB;
    const int tile = wave - b * WPB;
    const int j    = tile * COLS + lane - 3;     // lanes 0..2 = halo

    const int jc = j < 0 ? 0 : (j >= GC ? GC - 1 : j);
    const int jm = jc > 0 ? jc - 1 : 0;
    const bool jpos = (j >= 1);

    const size_t xb = (size_t)b * GN * 2;
    const size_t eb = (size_t)b * GE * 4;

    const float2 xc0 = *(const float2*)(x + xb + (size_t)jc * 2);
    const float2 xc1 = *(const float2*)(x + xb + ((size_t)GC + jc) * 2);
    const float4 ve1 = *(const float4*)(e + eb + (size_t)jm * 4);
    const float4 ve2 = *(const float4*)(e + eb + ((size_t)(GC - 1) + jm) * 4);
    const float4 ve3 = *(const float4*)(e + eb + ((size_t)(2 * (GC - 1)) + jc) * 4);

    float c0[2] = {xc0.x, xc0.y}, c1[2] = {xc1.x, xc1.y};
    float e1[4] = {ve1.x, ve1.y, ve1.z, ve1.w};
    float e2[4] = {ve2.x, ve2.y, ve2.z, ve2.w};
    float e3[4] = {ve3.x, ve3.y, ve3.z, ve3.w};

    // ---- layer 1: F=2, H=4, IN=8, O=4
    float h10[4], h11[4];
    layer<2, 4, 8, 4>(c0, c1, e1, e2, e3, w1a, b1a, w1b, b1b, jpos, h10, h11);

    // ---- layer 2: F=4, H=8, IN=12, O=8
    float h20[8], h21[8];
    layer<4, 8, 12, 8>(h10, h11, e1, e2, e3, w2a, b2a, w2b, b2b, jpos, h20, h21);

    // ---- layer 3: F=8, H=16, IN=20, O=16 — row0 second GEMM folded through mu
    float S0[16], S1[16];
    projF<8, 16, 20>(h20, w3a, 8, S0);
    projF<8, 16, 20>(h21, w3a, 8, S1);
    float S0p[16], S1p[16];
#pragma unroll
    for (int i = 0; i < 16; ++i) { S0p[i] = __shfl_up(S0[i], 1); S1p[i] = __shfl_up(S1[i], 1); }

    float t[16];
    // row0 horizontal edge, folded: mu0 = g_fold . relu(z) + g_fold[16]
    projE<16, 20>(e1, w3a, b3a, t);
    accF<8, 16, 20>(h20, w3a, 0, t);
    float mu0 = g_fold[16];
#pragma unroll
    for (int h = 0; h < 16; ++h)
        mu0 = fmaf(fmaxf(t[h] + S0p[h], 0.f), g_fold[h], mu0);

    float P1[16];
    projF<8, 16, 20>(h21, w3a, 0, P1);

    // row1 horizontal edge
    projE<16, 20>(e2, w3a, b3a, t);
    float Bv[16];
    zgemm3<16, 16>(t, P1, S1p, w3b, b3b, Bv);

    // vertical edge
    projE<16, 20>(e3, w3a, b3a, t);
    float V[16];
    zgemm3<16, 16>(t, P1, S0, w3b, b3b, V);

    float mu1 = 0.f;
#pragma unroll
    for (int h = 0; h < 16; ++h) {
        float v = jpos ? fmaxf(V[h], Bv[h]) : V[h];
        mu1 = fmaf(v, wmu[16 + h], mu1);
    }

    float mu = (jpos ? mu0 : 0.f) + mu1 + bmu[0];

    if (lane >= 3 && j < GC)
        out[(size_t)b * GC + j] = mu;
}

extern "C" void kernel_launch(void* const* d_in, const int* in_sizes, int n_in,
                              void* d_out, int out_size, void* d_ws, size_t ws_size,
                              hipStream_t stream) {
    const float* x   = (const float*)d_in[0];
    const float* e   = (const float*)d_in[1];
    // d_in[2]=src, d_in[3]=dst unused (structure is known statically)
    const float* w1a = (const float*)d_in[4];
    const float* b1a = (const float*)d_in[5];
    const float* w1b = (const float*)d_in[6];
    const float* b1b = (const float*)d_in[7];
    const float* w2a = (const float*)d_in[8];
    const float* b2a = (const float*)d_in[9];
    const float* w2b = (const float*)d_in[10];
    const float* b2b = (const float*)d_in[11];
    const float* w3a = (const float*)d_in[12];
    const float* b3a = (const float*)d_in[13];
    const float* w3b = (const float*)d_in[14];
    const float* b3b = (const float*)d_in[15];
    const float* wmu = (const float*)d_in[16];
    const float* bmu = (const float*)d_in[17];
    float* out = (float*)d_out;

    hipLaunchKernelGGL(fold_setup, dim3(1), dim3(64), 0, stream, w3b, b3b, wmu);

    constexpr int COLS = 61;
    constexpr int WPB = (GC + COLS - 1) / COLS;  // 538
    const int total_waves = 64 * WPB;            // 34432
    const int blocks = (total_waves * 64) / 256; // 8608

    hipLaunchKernelGGL(gnn_fused, dim3(blocks), dim3(256), 0, stream,
                       x, e, w1a, b1a, w1b, b1b, w2a, b2a, w2b, b2b,
                       w3a, b3a, w3b, b3b, wmu, bmu, out);
}

// Round 3
// 207.859 us; speedup vs baseline: 1.0638x; 1.0638x over previous
//
#include <hip/hip_runtime.h>

#define GC 32768
#define GN (2*GC)
#define GE (3*GC-2)

// Folded constants: g_fold[0..15] = wmu[0:16] @ w3b, g_fold[16] = wmu[0:16] . b3b
__device__ float g_fold[17];

__global__ void fold_setup(const float* __restrict__ w3b, const float* __restrict__ b3b,
                           const float* __restrict__ wmu) {
    int h = threadIdx.x;
    if (h < 16) {
        float a = 0.f;
        for (int o = 0; o < 16; ++o) a = fmaf(wmu[o], w3b[o * 16 + h], a);
        g_fold[h] = a;
    } else if (h == 16) {
        float a = 0.f;
        for (int o = 0; o < 16; ++o) a = fmaf(wmu[o], b3b[o], a);
        g_fold[16] = a;
    }
}

// msg = W2 @ relu(W1 @ [d; s; e] + B1) + B2   (R1 structure: one fused loop)
template<int F, int H, int O>
__device__ __forceinline__ void edge_msg(
    const float* d, const float* s, const float* ee,
    const float* __restrict__ W1, const float* __restrict__ B1,
    const float* __restrict__ W2, const float* __restrict__ B2,
    float* out)
{
    float z[H];
#pragma unroll
    for (int h = 0; h < H; ++h) {
        float acc = B1[h];
        const float* w = W1 + h * (2 * F + 4);
#pragma unroll
        for (int f = 0; f < F; ++f) acc = fmaf(d[f], w[f], acc);
#pragma unroll
        for (int f = 0; f < F; ++f) acc = fmaf(s[f], w[F + f], acc);
#pragma unroll
        for (int k = 0; k < 4; ++k) acc = fmaf(ee[k], w[2 * F + k], acc);
        z[h] = fmaxf(acc, 0.0f);
    }
#pragma unroll
    for (int o = 0; o < O; ++o) {
        float acc = B2[o];
#pragma unroll
        for (int h = 0; h < H; ++h) acc = fmaf(z[h], W2[o * H + h], acc);
        out[o] = acc;
    }
}

// dst-projection only: pre[h] = sum_f W1[h][f] * d[f]   (no bias)
template<int F, int H>
__device__ __forceinline__ void dstproj(const float* d, const float* __restrict__ W1,
                                        float* pre) {
#pragma unroll
    for (int h = 0; h < H; ++h) {
        const float* w = W1 + h * (2 * F + 4);
        float a = d[0] * w[0];
#pragma unroll
        for (int f = 1; f < F; ++f) a = fmaf(d[f], w[f], a);
        pre[h] = a;
    }
}

// z = relu(pre + B1 + Wsrc@s + We@e)  — seeded with shared dst-projection
template<int F, int H>
__device__ __forceinline__ void msg_z_pre(
    const float* pre, const float* s, const float* ee,
    const float* __restrict__ W1, const float* __restrict__ B1, float* z)
{
#pragma unroll
    for (int h = 0; h < H; ++h) {
        const float* w = W1 + h * (2 * F + 4);
        float acc = pre[h] + B1[h];
#pragma unroll
        for (int f = 0; f < F; ++f) acc = fmaf(s[f], w[F + f], acc);
#pragma unroll
        for (int k = 0; k < 4; ++k) acc = fmaf(ee[k], w[2 * F + k], acc);
        z[h] = fmaxf(acc, 0.0f);
    }
}

template<int H, int O>
__device__ __forceinline__ void gemm2(const float* z,
                                      const float* __restrict__ W2,
                                      const float* __restrict__ B2, float* out) {
#pragma unroll
    for (int o = 0; o < O; ++o) {
        float acc = B2[o];
#pragma unroll
        for (int h = 0; h < H; ++h) acc = fmaf(z[h], W2[o * H + h], acc);
        out[o] = acc;
    }
}

// One edge-conv layer (R1 shape, with row1 dst-proj shared between its 2 edges)
template<int F, int H, int O>
__device__ __forceinline__ void layer_step(
    const float* c0, const float* c1, const float* p0, const float* p1,
    const float* eh1, const float* eh2, const float* ev, bool jpos,
    const float* __restrict__ W1, const float* __restrict__ B1,
    const float* __restrict__ W2, const float* __restrict__ B2,
    float* o0, float* o1)
{
    float A[O];
    edge_msg<F, H, O>(c0, p0, eh1, W1, B1, W2, B2, A);   // row0: dst=j, src=j-1

    float P1[H];
    dstproj<F, H>(c1, W1, P1);                           // shared dst-proj of row1

    float zB[H], Bv[O];
    msg_z_pre<F, H>(P1, p1, eh2, W1, B1, zB);            // row1 horizontal
    gemm2<H, O>(zB, W2, B2, Bv);

    float zV[H], V[O];
    msg_z_pre<F, H>(P1, c0, ev, W1, B1, zV);             // vertical: dst=row1, src=row0
    gemm2<H, O>(zV, W2, B2, V);

#pragma unroll
    for (int o = 0; o < O; ++o) {
        o0[o] = jpos ? A[o] : 0.0f;                // node 0 row0: no in-edges -> 0
        o1[o] = jpos ? fmaxf(V[o], Bv[o]) : V[o];  // segment_max over <=2 edges
    }
}

__global__ __launch_bounds__(256) void gnn_fused(
    const float* __restrict__ x, const float* __restrict__ e,
    const float* __restrict__ w1a, const float* __restrict__ b1a,
    const float* __restrict__ w1b, const float* __restrict__ b1b,
    const float* __restrict__ w2a, const float* __restrict__ b2a,
    const float* __restrict__ w2b, const float* __restrict__ b2b,
    const float* __restrict__ w3a, const float* __restrict__ b3a,
    const float* __restrict__ w3b, const float* __restrict__ b3b,
    const float* __restrict__ wmu, const float* __restrict__ bmu,
    float* __restrict__ out)
{
    constexpr int WPB = (GC + 61) / 62;  // 529 waves per batch row
    const int gtid = blockIdx.x * blockDim.x + threadIdx.x;
    const int wave = gtid >> 6;
    const int lane = gtid & 63;
    const int b    = wave / WPB;
    const int tile = wave - b * WPB;
    const int j    = tile * 62 + lane - 2;   // lanes 0,1 = halo

    const int jc = j < 0 ? 0 : (j >= GC ? GC - 1 : j);
    const int jm = jc > 0 ? jc - 1 : 0;
    const bool jpos = (j >= 1);

    const size_t xb = (size_t)b * GN * 2;
    const size_t eb = (size_t)b * GE * 4;

    const float2 xc0 = *(const float2*)(x + xb + (size_t)jc * 2);
    const float2 xp0 = *(const float2*)(x + xb + (size_t)jm * 2);
    const float2 xc1 = *(const float2*)(x + xb + ((size_t)GC + jc) * 2);
    const float2 xp1 = *(const float2*)(x + xb + ((size_t)GC + jm) * 2);
    const float4 v_eh1 = *(const float4*)(e + eb + (size_t)jm * 4);
    const float4 v_eh2 = *(const float4*)(e + eb + ((size_t)(GC - 1) + jm) * 4);
    const float4 v_ev  = *(const float4*)(e + eb + ((size_t)(2 * (GC - 1)) + jc) * 4);

    float c0[2] = {xc0.x, xc0.y}, c1[2] = {xc1.x, xc1.y};
    float p0[2] = {xp0.x, xp0.y}, p1[2] = {xp1.x, xp1.y};
    float eh1[4] = {v_eh1.x, v_eh1.y, v_eh1.z, v_eh1.w};
    float eh2[4] = {v_eh2.x, v_eh2.y, v_eh2.z, v_eh2.w};
    float ev[4]  = {v_ev.x,  v_ev.y,  v_ev.z,  v_ev.w};

    // ---- layer 1: F=2 -> H=4 -> O=4
    float h10[4], h11[4];
    layer_step<2, 4, 4>(c0, c1, p0, p1, eh1, eh2, ev, jpos,
                        w1a, b1a, w1b, b1b, h10, h11);

    float q10[4], q11[4];
#pragma unroll
    for (int i = 0; i < 4; ++i) {
        q10[i] = __shfl_up(h10[i], 1);
        q11[i] = __shfl_up(h11[i], 1);
    }

    // ---- layer 2: F=4 -> H=8 -> O=8
    float h20[8], h21[8];
    layer_step<4, 8, 8>(h10, h11, q10, q11, eh1, eh2, ev, jpos,
                        w2a, b2a, w2b, b2b, h20, h21);

    float q20[8], q21[8];
#pragma unroll
    for (int i = 0; i < 8; ++i) {
        q20[i] = __shfl_up(h20[i], 1);
        q21[i] = __shfl_up(h21[i], 1);
    }

    // ---- layer 3: F=8 -> H=16 -> O=16, row0 second GEMM folded through mu
    // row0 horizontal edge: z0 = relu(Wd@h20 + Ws@q20 + We@e1 + b3a)
    float mu0 = g_fold[16];
#pragma unroll
    for (int h = 0; h < 16; ++h) {
        const float* w = w3a + h * 20;
        float acc = b3a[h];
#pragma unroll
        for (int f = 0; f < 8; ++f) acc = fmaf(h20[f], w[f], acc);
#pragma unroll
        for (int f = 0; f < 8; ++f) acc = fmaf(q20[f], w[8 + f], acc);
#pragma unroll
        for (int k = 0; k < 4; ++k) acc = fmaf(eh1[k], w[16 + k], acc);
        mu0 = fmaf(fmaxf(acc, 0.0f), g_fold[h], mu0);
    }

    // row1 edges with shared dst-proj
    float P1[16];
    dstproj<8, 16>(h21, w3a, P1);

    float zB[16], Bv[16];
    msg_z_pre<8, 16>(P1, q21, eh2, w3a, b3a, zB);
    gemm2<16, 16>(zB, w3b, b3b, Bv);

    float zV[16], V[16];
    msg_z_pre<8, 16>(P1, h20, ev, w3a, b3a, zV);
    gemm2<16, 16>(zV, w3b, b3b, V);

    float mu1 = 0.f;
#pragma unroll
    for (int h = 0; h < 16; ++h) {
        float v = jpos ? fmaxf(V[h], Bv[h]) : V[h];
        mu1 = fmaf(v, wmu[16 + h], mu1);
    }

    float mu = (jpos ? mu0 : 0.f) + mu1 + bmu[0];

    if (lane >= 2 && j < GC)
        out[(size_t)b * GC + j] = mu;
}

extern "C" void kernel_launch(void* const* d_in, const int* in_sizes, int n_in,
                              void* d_out, int out_size, void* d_ws, size_t ws_size,
                              hipStream_t stream) {
    const float* x   = (const float*)d_in[0];
    const float* e   = (const float*)d_in[1];
    // d_in[2]=src, d_in[3]=dst unused (structure is known statically)
    const float* w1a = (const float*)d_in[4];
    const float* b1a = (const float*)d_in[5];
    const float* w1b = (const float*)d_in[6];
    const float* b1b = (const float*)d_in[7];
    const float* w2a = (const float*)d_in[8];
    const float* b2a = (const float*)d_in[9];
    const float* w2b = (const float*)d_in[10];
    const float* b2b = (const float*)d_in[11];
    const float* w3a = (const float*)d_in[12];
    const float* b3a = (const float*)d_in[13];
    const float* w3b = (const float*)d_in[14];
    const float* b3b = (const float*)d_in[15];
    const float* wmu = (const float*)d_in[16];
    const float* bmu = (const float*)d_in[17];
    float* out = (float*)d_out;

    hipLaunchKernelGGL(fold_setup, dim3(1), dim3(64), 0, stream, w3b, b3b, wmu);

    constexpr int WPB = (GC + 61) / 62;          // 529
    const int total_waves = 64 * WPB;            // 33856
    const int blocks = (total_waves * 64) / 256; // 8464

    hipLaunchKernelGGL(gnn_fused, dim3(blocks), dim3(256), 0, stream,
                       x, e, w1a, b1a, w1b, b1b, w2a, b2a, w2b, b2b,
                       w3a, b3a, w3b, b3b, wmu, bmu, out);
}

// Round 4
// 185.844 us; speedup vs baseline: 1.1899x; 1.1185x over previous
//
#include <hip/hip_runtime.h>

#define GC 32768
#define GN (2*GC)
#define GE (3*GC-2)

typedef float v2f __attribute__((ext_vector_type(2)));

__device__ __forceinline__ v2f vsplat(float s) { v2f r = {s, s}; return r; }
__device__ __forceinline__ v2f vfma(v2f a, float w, v2f c) {
    return __builtin_elementwise_fma(a, vsplat(w), c);
}
__device__ __forceinline__ v2f vmax2(v2f a, v2f b) { return __builtin_elementwise_max(a, b); }

// Folded constants: g_fold[0..15] = wmu[0:16] @ w3b, g_fold[16] = wmu[0:16] . b3b
__device__ float g_fold[17];

__global__ void fold_setup(const float* __restrict__ w3b, const float* __restrict__ b3b,
                           const float* __restrict__ wmu) {
    int h = threadIdx.x;
    if (h < 16) {
        float a = 0.f;
        for (int o = 0; o < 16; ++o) a = fmaf(wmu[o], w3b[o * 16 + h], a);
        g_fold[h] = a;
    } else if (h == 16) {
        float a = 0.f;
        for (int o = 0; o < 16; ++o) a = fmaf(wmu[o], b3b[o], a);
        g_fold[16] = a;
    }
}

// msg = W2 @ relu(W1 @ [d; s; e] + B1) + B2, two columns at once (packed fp32)
template<int F, int H, int O>
__device__ __forceinline__ void edge_msg2(
    const v2f* d, const v2f* s, const v2f* ee,
    const float* __restrict__ W1, const float* __restrict__ B1,
    const float* __restrict__ W2, const float* __restrict__ B2,
    v2f* out)
{
    v2f z[H];
#pragma unroll
    for (int h = 0; h < H; ++h) {
        const float* w = W1 + h * (2 * F + 4);
        v2f acc = vsplat(B1[h]);
#pragma unroll
        for (int f = 0; f < F; ++f) acc = vfma(d[f], w[f], acc);
#pragma unroll
        for (int f = 0; f < F; ++f) acc = vfma(s[f], w[F + f], acc);
#pragma unroll
        for (int k = 0; k < 4; ++k) acc = vfma(ee[k], w[2 * F + k], acc);
        z[h] = vmax2(acc, vsplat(0.f));
    }
#pragma unroll
    for (int o = 0; o < O; ++o) {
        v2f acc = vsplat(B2[o]);
#pragma unroll
        for (int h = 0; h < H; ++h) acc = vfma(z[h], W2[o * H + h], acc);
        out[o] = acc;
    }
}

// segment_max combine for the pair; jx = (j0 >= 1); .y component (j1=j0+1) always >=1
template<int O>
__device__ __forceinline__ void combine(const v2f* A, const v2f* Bv, const v2f* V,
                                        bool jx, v2f* o0, v2f* o1) {
#pragma unroll
    for (int o = 0; o < O; ++o) {
        v2f a = A[o];
        o0[o].x = jx ? a.x : 0.f;   // col 0 row0: no in-edges -> 0
        o0[o].y = a.y;
        v2f m = vmax2(V[o], Bv[o]);
        o1[o].x = jx ? m.x : V[o].x; // col 0 row1: vertical edge only
        o1[o].y = m.y;
    }
}

// previous-column pair: prev of j0 = lane-1's .y ; prev of j1 = own .x
template<int N>
__device__ __forceinline__ void shift_prev(const v2f* h, v2f* q) {
#pragma unroll
    for (int i = 0; i < N; ++i) {
        q[i].x = __shfl_up(h[i].y, 1);
        q[i].y = h[i].x;
    }
}

__global__ __launch_bounds__(256) void gnn_fused(
    const float* __restrict__ x, const float* __restrict__ e,
    const float* __restrict__ w1a, const float* __restrict__ b1a,
    const float* __restrict__ w1b, const float* __restrict__ b1b,
    const float* __restrict__ w2a, const float* __restrict__ b2a,
    const float* __restrict__ w2b, const float* __restrict__ b2b,
    const float* __restrict__ w3a, const float* __restrict__ b3a,
    const float* __restrict__ w3b, const float* __restrict__ b3b,
    const float* __restrict__ wmu, const float* __restrict__ bmu,
    float* __restrict__ out)
{
    constexpr int COLS = 124;                    // valid columns per wave (62 lanes x 2)
    constexpr int WPB = (GC + COLS - 1) / COLS;  // 265 waves per batch row
    const int gtid = blockIdx.x * blockDim.x + threadIdx.x;
    const int wave = gtid >> 6;
    const int lane = gtid & 63;
    const int b    = wave / WPB;
    const int tile = wave - b * WPB;
    const int j0   = tile * COLS + 2 * lane - 4; // lanes 0,1 = halo pairs

    const int jc0 = j0 < 0 ? 0 : (j0 > GC - 2 ? GC - 2 : j0);
    const int jm0 = jc0 > 0 ? jc0 - 1 : 0;
    const bool jx = (j0 >= 1);

    const size_t xb = (size_t)b * GN * 2;
    const size_t eb = (size_t)b * GE * 4;

    // x features for cols (j0, j0+1) and col j0-1, both rows
    const float4 x0  = *(const float4*)(x + xb + 2 * (size_t)jc0);
    const float2 xp0 = *(const float2*)(x + xb + 2 * (size_t)jm0);
    const float4 x1  = *(const float4*)(x + xb + 2 * (size_t)(GC + jc0));
    const float2 xp1 = *(const float2*)(x + xb + 2 * (size_t)(GC + jm0));

    v2f c0f[2] = {{x0.x, x0.z}, {x0.y, x0.w}};
    v2f p0f[2] = {{xp0.x, x0.x}, {xp0.y, x0.y}};
    v2f c1f[2] = {{x1.x, x1.z}, {x1.y, x1.w}};
    v2f p1f[2] = {{xp1.x, x1.x}, {xp1.y, x1.y}};

    // edge features, packed per pair
    const float4 eA1 = *(const float4*)(e + eb + 4 * (size_t)jm0);
    const float4 eB1 = *(const float4*)(e + eb + 4 * (size_t)jc0);
    const float4 eA2 = *(const float4*)(e + eb + 4 * (size_t)(GC - 1 + jm0));
    const float4 eB2 = *(const float4*)(e + eb + 4 * (size_t)(GC - 1 + jc0));
    const float4 eA3 = *(const float4*)(e + eb + 4 * (size_t)(2 * (GC - 1) + jc0));
    const float4 eB3 = *(const float4*)(e + eb + 4 * (size_t)(2 * (GC - 1) + jc0 + 1));

    v2f e1f[4] = {{eA1.x, eB1.x}, {eA1.y, eB1.y}, {eA1.z, eB1.z}, {eA1.w, eB1.w}};
    v2f e2f[4] = {{eA2.x, eB2.x}, {eA2.y, eB2.y}, {eA2.z, eB2.z}, {eA2.w, eB2.w}};
    v2f e3f[4] = {{eA3.x, eB3.x}, {eA3.y, eB3.y}, {eA3.z, eB3.z}, {eA3.w, eB3.w}};

    // ---- layer 1: F=2 -> H=4 -> O=4
    v2f A1[4], B1v[4], V1[4];
    edge_msg2<2, 4, 4>(c0f, p0f, e1f, w1a, b1a, w1b, b1b, A1);   // row0 horizontal
    edge_msg2<2, 4, 4>(c1f, p1f, e2f, w1a, b1a, w1b, b1b, B1v);  // row1 horizontal
    edge_msg2<2, 4, 4>(c1f, c0f, e3f, w1a, b1a, w1b, b1b, V1);   // vertical
    v2f h10[4], h11[4];
    combine<4>(A1, B1v, V1, jx, h10, h11);

    v2f q10[4], q11[4];
    shift_prev<4>(h10, q10);
    shift_prev<4>(h11, q11);

    // ---- layer 2: F=4 -> H=8 -> O=8
    v2f A2[8], B2v[8], V2[8];
    edge_msg2<4, 8, 8>(h10, q10, e1f, w2a, b2a, w2b, b2b, A2);
    edge_msg2<4, 8, 8>(h11, q11, e2f, w2a, b2a, w2b, b2b, B2v);
    edge_msg2<4, 8, 8>(h11, h10, e3f, w2a, b2a, w2b, b2b, V2);
    v2f h20[8], h21[8];
    combine<8>(A2, B2v, V2, jx, h20, h21);

    v2f q20[8], q21[8];
    shift_prev<8>(h20, q20);
    shift_prev<8>(h21, q21);

    // ---- layer 3: F=8 -> H=16 -> O=16; row0 second GEMM folded through mu
    v2f mu0 = vsplat(g_fold[16]);
#pragma unroll
    for (int h = 0; h < 16; ++h) {
        const float* w = w3a + h * 20;
        v2f acc = vsplat(b3a[h]);
#pragma unroll
        for (int f = 0; f < 8; ++f) acc = vfma(h20[f], w[f], acc);
#pragma unroll
        for (int f = 0; f < 8; ++f) acc = vfma(q20[f], w[8 + f], acc);
#pragma unroll
        for (int k = 0; k < 4; ++k) acc = vfma(e1f[k], w[16 + k], acc);
        mu0 = vfma(vmax2(acc, vsplat(0.f)), g_fold[h], mu0);
    }

    v2f Bv[16], V[16];
    edge_msg2<8, 16, 16>(h21, q21, e2f, w3a, b3a, w3b, b3b, Bv);
    edge_msg2<8, 16, 16>(h21, h20, e3f, w3a, b3a, w3b, b3b, V);

    v2f mu1 = vsplat(0.f);
#pragma unroll
    for (int h = 0; h < 16; ++h) {
        v2f m = vmax2(V[h], Bv[h]);
        v2f sel;
        sel.x = jx ? m.x : V[h].x;
        sel.y = m.y;
        mu1 = vfma(sel, wmu[16 + h], mu1);
    }

    const float bm = bmu[0];
    const float outx = (jx ? mu0.x : 0.f) + mu1.x + bm;
    const float outy = mu0.y + mu1.y + bm;

    if (lane >= 2 && j0 >= 0 && j0 < GC)
        *(float2*)(out + (size_t)b * GC + j0) = make_float2(outx, outy);
}

extern "C" void kernel_launch(void* const* d_in, const int* in_sizes, int n_in,
                              void* d_out, int out_size, void* d_ws, size_t ws_size,
                              hipStream_t stream) {
    const float* x   = (const float*)d_in[0];
    const float* e   = (const float*)d_in[1];
    // d_in[2]=src, d_in[3]=dst unused (structure is known statically)
    const float* w1a = (const float*)d_in[4];
    const float* b1a = (const float*)d_in[5];
    const float* w1b = (const float*)d_in[6];
    const float* b1b = (const float*)d_in[7];
    const float* w2a = (const float*)d_in[8];
    const float* b2a = (const float*)d_in[9];
    const float* w2b = (const float*)d_in[10];
    const float* b2b = (const float*)d_in[11];
    const float* w3a = (const float*)d_in[12];
    const float* b3a = (const float*)d_in[13];
    const float* w3b = (const float*)d_in[14];
    const float* b3b = (const float*)d_in[15];
    const float* wmu = (const float*)d_in[16];
    const float* bmu = (const float*)d_in[17];
    float* out = (float*)d_out;

    hipLaunchKernelGGL(fold_setup, dim3(1), dim3(64), 0, stream, w3b, b3b, wmu);

    constexpr int COLS = 124;
    constexpr int WPB = (GC + COLS - 1) / COLS;      // 265
    const int total_waves = 64 * WPB;                // 16960
    const int blocks = (total_waves * 64) / 256;     // 4240

    hipLaunchKernelGGL(gnn_fused, dim3(blocks), dim3(256), 0, stream,
                       x, e, w1a, b1a, w1b, b1b, w2a, b2a, w2b, b2b,
                       w3a, b3a, w3b, b3b, wmu, bmu, out);
}